// Round 5
// baseline (121.992 us; speedup 1.0000x reference)
//
#include <hip/hip_runtime.h>
#include <hip/hip_bf16.h>

// B=1024, M=4 segments, L=100 tokens, D=512, V=50000, H=512, DEC_HID=128
constexpr int NB   = 1024;
constexpr int NSEG = 4;
constexpr int LSEQ = 100;
constexpr int ND   = 512;
constexpr int NH   = 512;
constexpr int NDEC = 128;
constexpr int NV   = 50000;
constexpr int NSLICE = 8;
constexpr int SLICE_ROWS = NV / NSLICE;            // 6250
constexpr size_t TBL_ELEMS = (size_t)NV * ND;      // 25.6M elems

typedef __attribute__((ext_vector_type(8))) short bf16x8;
typedef __attribute__((ext_vector_type(4))) float f32x4;
typedef __attribute__((ext_vector_type(2))) float f32x2;
typedef __attribute__((ext_vector_type(8))) unsigned short u16x8;

__device__ __forceinline__ ushort f2bf(float f) {
    union { float f; unsigned u; } v; v.f = f;
    unsigned r = (v.u + 0x7fffu + ((v.u >> 16) & 1u)) >> 16;   // RNE
    return (ushort)r;
}
__device__ __forceinline__ float bf2f(ushort u) {
    return __uint_as_float((unsigned)u << 16);
}

// global -> LDS direct copy, 16 B per lane. LDS dest wave-uniform base;
// lane i lands at base + i*16. Global src is per-lane (fragment-ordered).
#define GLOAD_LDS16(gp, lp)                                                     \
    __builtin_amdgcn_global_load_lds(                                           \
        (const __attribute__((address_space(1))) unsigned int*)(gp),            \
        (__attribute__((address_space(3))) unsigned int*)(lp), 16, 0, 0)

#define VMW(N) asm volatile("s_waitcnt vmcnt(" #N ")" ::: "memory")
#define RBAR() do { __builtin_amdgcn_s_barrier();                               \
                    __builtin_amdgcn_sched_barrier(0); } while (0)

// ---------------------------------------------------------------------------
// One-shot conversion: embed table fp32->fp8 e4m3 (hardware cvt),
// 6 weight matrices fp32->bf16, RNN bias pairs pre-summed.
// ---------------------------------------------------------------------------
__global__ __launch_bounds__(256)
void convert_all(const float* __restrict__ table,
                 const float* __restrict__ w_ih0, const float* __restrict__ w_hh0,
                 const float* __restrict__ w_ih1, const float* __restrict__ w_hh1,
                 const float* __restrict__ w_d1,  const float* __restrict__ w_d2,
                 const float* __restrict__ b_ih0, const float* __restrict__ b_hh0,
                 const float* __restrict__ b_ih1, const float* __restrict__ b_hh1,
                 unsigned* __restrict__ tb8, ushort* __restrict__ wbf,
                 float* __restrict__ bsum0, float* __restrict__ bsum1,
                 int doTable)
{
    const size_t stride = (size_t)gridDim.x * blockDim.x;
    const size_t gid    = (size_t)blockIdx.x * blockDim.x + threadIdx.x;

    if (doTable) {
        const size_t nvec = TBL_ELEMS / 8;     // 8 floats -> 8 fp8 bytes
        for (size_t i = gid; i < nvec; i += stride) {
            const float4 a = ((const float4*)table)[2 * i];
            const float4 b = ((const float4*)table)[2 * i + 1];
            unsigned w0 = __builtin_amdgcn_cvt_pk_fp8_f32(a.x, a.y, 0, false);
            w0          = __builtin_amdgcn_cvt_pk_fp8_f32(a.z, a.w, w0, true);
            unsigned w1 = __builtin_amdgcn_cvt_pk_fp8_f32(b.x, b.y, 0, false);
            w1          = __builtin_amdgcn_cvt_pk_fp8_f32(b.z, b.w, w1, true);
            uint2 o; o.x = w0; o.y = w1;
            ((uint2*)tb8)[i] = o;
        }
    }
    constexpr int N0 = 512 * 512, ND2 = 128 * 512;
    constexpr int TOT = 4 * N0 + 2 * ND2 + 1024;
    for (size_t i = gid; i < TOT; i += stride) {
        if (i < 4 * (size_t)N0) {
            const float* src = (i < N0) ? w_ih0 : (i < 2*(size_t)N0) ? w_hh0
                             : (i < 3*(size_t)N0) ? w_ih1 : w_hh1;
            wbf[i] = f2bf(src[i & (N0 - 1)]);
        } else if (i < 4 * (size_t)N0 + ND2) {
            wbf[i] = f2bf(w_d1[i - 4 * (size_t)N0]);
        } else if (i < 4 * (size_t)N0 + 2 * ND2) {
            wbf[i] = f2bf(w_d2[i - 4 * (size_t)N0 - ND2]);
        } else {
            const int j = (int)(i - (4 * (size_t)N0 + 2 * ND2));
            if (j < 512) bsum0[j] = b_ih0[j] + b_hh0[j];
            else         bsum1[j - 512] = b_ih1[j - 512] + b_hh1[j - 512];
        }
    }
}

// ---------------------------------------------------------------------------
// Pool phase A: vocab-sliced partial sums. Block gid: slice = gid&7 (lands on
// XCD gid&7 by round-robin), 4 waves = 4 consecutive (b,m). Each wave
// compacts its 100 tokens to those in [slice*6250, (slice+1)*6250), gathers
// fp8 rows (slice is L2-resident: 3.2 MB), and writes a bf16 partial sum
// (non-temporal, so partials don't evict the slice) + a count.
// Masked-out past segments are skipped entirely (ref multiplies them by 0).
// ---------------------------------------------------------------------------
__global__ __launch_bounds__(256)
void poolA(const int* __restrict__ toks, const unsigned char* __restrict__ tb8,
           const float* __restrict__ masks,
           ushort* __restrict__ partial, unsigned* __restrict__ cnts)
{
    const int gid   = blockIdx.x;
    const int slice = gid & 7;
    const int wv    = threadIdx.x >> 6;
    const int lane  = threadIdx.x & 63;
    const int bm    = (gid >> 3) * 4 + wv;
    const int m     = bm & 3;

    __shared__ int sidx[4][112];
    int* sw = sidx[wv];

    if (m != 1 && masks[bm] == 0.0f) return;   // partial never read for these

    const int lo = slice * SLICE_ROWS, hi = lo + SLICE_ROWS;
    const unsigned long long lmlt = (1ull << lane) - 1ull;
    int cnt;
    {
        const int t0 = __builtin_nontemporal_load(&toks[(size_t)bm * LSEQ + lane]);
        const bool v0 = (t0 != 0) & (t0 >= lo) & (t0 < hi);
        const unsigned long long b0 = __ballot(v0);
        if (v0) sw[__popcll(b0 & lmlt)] = t0;
        cnt = __popcll(b0);
        int t1 = 0;
        if (lane < LSEQ - 64)
            t1 = __builtin_nontemporal_load(&toks[(size_t)bm * LSEQ + 64 + lane]);
        const bool v1 = (t1 != 0) & (t1 >= lo) & (t1 < hi);
        const unsigned long long b1 = __ballot(v1);
        if (v1) sw[cnt + __popcll(b1 & lmlt)] = t1;
        cnt += __popcll(b1);
    }
    asm volatile("s_waitcnt lgkmcnt(0)" ::: "memory");   // per-wave LDS list ready
    __builtin_amdgcn_sched_barrier(0);

    float acc[8] = {};
    const size_t off = (size_t)lane * 8;
    int j = 0;
    for (; j + 4 <= cnt; j += 4) {
        uint2 v[4];
        #pragma unroll
        for (int u = 0; u < 4; ++u)
            v[u] = *(const uint2*)&tb8[(size_t)sw[j + u] * ND + off];
        #pragma unroll
        for (int u = 0; u < 4; ++u) {
            const f32x2 p0 = __builtin_amdgcn_cvt_pk_f32_fp8(v[u].x, false);
            const f32x2 p1 = __builtin_amdgcn_cvt_pk_f32_fp8(v[u].x, true);
            const f32x2 p2 = __builtin_amdgcn_cvt_pk_f32_fp8(v[u].y, false);
            const f32x2 p3 = __builtin_amdgcn_cvt_pk_f32_fp8(v[u].y, true);
            acc[0] += p0[0]; acc[1] += p0[1]; acc[2] += p1[0]; acc[3] += p1[1];
            acc[4] += p2[0]; acc[5] += p2[1]; acc[6] += p3[0]; acc[7] += p3[1];
        }
    }
    for (; j < cnt; ++j) {
        const uint2 v = *(const uint2*)&tb8[(size_t)sw[j] * ND + off];
        const f32x2 p0 = __builtin_amdgcn_cvt_pk_f32_fp8(v.x, false);
        const f32x2 p1 = __builtin_amdgcn_cvt_pk_f32_fp8(v.x, true);
        const f32x2 p2 = __builtin_amdgcn_cvt_pk_f32_fp8(v.y, false);
        const f32x2 p3 = __builtin_amdgcn_cvt_pk_f32_fp8(v.y, true);
        acc[0] += p0[0]; acc[1] += p0[1]; acc[2] += p1[0]; acc[3] += p1[1];
        acc[4] += p2[0]; acc[5] += p2[1]; acc[6] += p3[0]; acc[7] += p3[1];
    }

    u16x8 o;
    #pragma unroll
    for (int e = 0; e < 8; ++e) o[e] = f2bf(acc[e]);
    __builtin_nontemporal_store(o,
        (u16x8*)&partial[((size_t)bm * NSLICE + slice) * ND + lane * 8]);
    if (lane == 0) cnts[bm * NSLICE + slice] = (unsigned)cnt;
}

// ---------------------------------------------------------------------------
// Pool phase B: reduce 8 bf16 partials + counts, normalize.
// m==1 -> fp32 x_future into d_out; else bf16 xpool (zeros if masked out).
// ---------------------------------------------------------------------------
__global__ __launch_bounds__(256)
void poolB(const ushort* __restrict__ partial, const unsigned* __restrict__ cnts,
           const float* __restrict__ masks,
           ushort* __restrict__ xpool, float* __restrict__ xfut)
{
    const int bm   = blockIdx.x * 4 + (threadIdx.x >> 6);
    const int lane = threadIdx.x & 63;
    const int m    = bm & 3;
    const int d    = lane * 8;

    if (m != 1 && masks[bm] == 0.0f) {
        u16x8 z = {};
        *(u16x8*)&xpool[(size_t)bm * ND + d] = z;
        return;
    }
    float acc[8] = {};
    unsigned cnt = 0;
    #pragma unroll
    for (int jj = 0; jj < NSLICE; ++jj) {
        const u16x8 p = __builtin_nontemporal_load(
            (const u16x8*)&partial[((size_t)bm * NSLICE + jj) * ND + d]);
        #pragma unroll
        for (int e = 0; e < 8; ++e) acc[e] += bf2f(p[e]);
        cnt += cnts[bm * NSLICE + jj];
    }
    const float inv = 1.0f / (float)(cnt > 0 ? cnt : 1);
    if (m == 1) {
        float* dst = &xfut[(size_t)(bm >> 2) * ND + d];
        float4 o0 = {acc[0]*inv, acc[1]*inv, acc[2]*inv, acc[3]*inv};
        float4 o1 = {acc[4]*inv, acc[5]*inv, acc[6]*inv, acc[7]*inv};
        *(float4*)dst = o0; *(float4*)(dst + 4) = o1;
    } else {
        u16x8 o;
        #pragma unroll
        for (int e = 0; e < 8; ++e) o[e] = f2bf(acc[e] * inv);
        *(u16x8*)&xpool[(size_t)bm * ND + d] = o;
    }
}

// ---------------------------------------------------------------------------
// Fallback single-phase pool (fp32 table) if workspace is too small.
// ---------------------------------------------------------------------------
__global__ __launch_bounds__(64)
void pool_fallback(const int* __restrict__ toks, const float* __restrict__ tb,
                   const float* __restrict__ masks,
                   ushort* __restrict__ xpool, float* __restrict__ xfut)
{
    const int bm = blockIdx.x, m = bm & 3, lane = threadIdx.x;
    __shared__ int sidx[LSEQ];
    int cnt = 0;
    {
        const int t0 = toks[(size_t)bm * LSEQ + lane];
        const unsigned long long m0 = __ballot(t0 != 0);
        const int p0 = __popcll(m0 & ((1ull << lane) - 1ull));
        if (t0 != 0) sidx[p0] = t0;
        cnt = __popcll(m0);
        const int t1 = (lane < LSEQ - 64) ? toks[(size_t)bm * LSEQ + 64 + lane] : 0;
        const unsigned long long m1 = __ballot(t1 != 0);
        const int p1 = __popcll(m1 & ((1ull << lane) - 1ull));
        if (t1 != 0) sidx[cnt + p1] = t1;
        cnt += __popcll(m1);
    }
    __syncthreads();
    const int d = lane * 8;
    float acc[8] = {};
    for (int j = 0; j < cnt; ++j) {
        const float4 a = *(const float4*)&tb[(size_t)sidx[j] * ND + d];
        const float4 b = *(const float4*)&tb[(size_t)sidx[j] * ND + d + 4];
        acc[0] += a.x; acc[1] += a.y; acc[2] += a.z; acc[3] += a.w;
        acc[4] += b.x; acc[5] += b.y; acc[6] += b.z; acc[7] += b.w;
    }
    const float inv = 1.0f / (float)(cnt > 0 ? cnt : 1);
    if (m == 1) {
        float* dst = &xfut[(size_t)(bm >> 2) * ND + d];
        float4 o0 = {acc[0]*inv, acc[1]*inv, acc[2]*inv, acc[3]*inv};
        float4 o1 = {acc[4]*inv, acc[5]*inv, acc[6]*inv, acc[7]*inv};
        *(float4*)dst = o0; *(float4*)(dst + 4) = o1;
    } else {
        const float sc = masks[bm] * inv;
        u16x8 o;
        #pragma unroll
        for (int e = 0; e < 8; ++e) o[e] = f2bf(acc[e] * sc);
        *(u16x8*)&xpool[(size_t)bm * ND + d] = o;
    }
}

// ---------------------------------------------------------------------------
// bf16 MFMA GEMM, pipelined: C = act( [A0, A1] @ [W0, W1]^T + bias )
// 64x64 tile, BK=64, 256 threads = 4 waves (2x2 of 32x32 quadrants).
// 4-slot LDS pipeline, prefetch depth 3, counted vmcnt(12) + raw s_barrier.
// Chunked XCD swizzle: XCD k owns contiguous row-tiles (A local, h panels
// produced and consumed on the same XCD across the RNN chain).
// ---------------------------------------------------------------------------
template<bool RELU, bool WF32, bool WBF>
__global__ __launch_bounds__(256)
void mfma_gemm(const ushort* __restrict__ A0, int lda0,
               const ushort* __restrict__ A1, int lda1,
               const ushort* __restrict__ W0, int ldw0,
               const ushort* __restrict__ W1, int ldw1,
               const float* __restrict__ bias,
               float* __restrict__ Cf, ushort* __restrict__ Cb, int ldc,
               int K0, int K1, int gx)
{
    __shared__ ushort SB[4][8192];    // 4 slots x (A 8KB | W 8KB)
    const int tid  = threadIdx.x;
    const int lane = tid & 63;
    const int wid  = tid >> 6;        // 0..3
    const int l15  = lane & 15;
    const int sl   = lane >> 4;       // k-chunk slot within 32-k group
    const int wr   = wid >> 1;        // quadrant row (0/1)
    const int wc   = wid & 1;         // quadrant col (0/1)

    const int per  = gridDim.x >> 3;
    const int tile = (blockIdx.x & 7) * per + (blockIdx.x >> 3);  // row-major id
    const int row0 = (tile / gx) * 64;
    const int col0 = (tile % gx) * 64;
    const int nt   = (K0 + K1) >> 6;  // K-steps of 64

    f32x4 acc[2][2] = {};

    auto STAGE = [&](int t) {
        if (t >= nt) return;
        const int kg   = t * 64;
        const int ph   = (kg >= K0);
        const int koff = ph ? kg - K0 : kg;
        const ushort* Ap = ph ? A1 : A0;
        const int     la = ph ? lda1 : lda0;
        const ushort* Wp = ph ? W1 : W0;
        const int     lw = ph ? ldw1 : ldw0;
        ushort* dst = &SB[t & 3][0];
        const ushort* ga = Ap + (size_t)(row0 + wid * 16 + l15) * la + koff + sl * 8;
        GLOAD_LDS16(ga,      dst + (wid * 2 + 0) * 512);
        GLOAD_LDS16(ga + 32, dst + (wid * 2 + 1) * 512);
        const ushort* gw = Wp + (size_t)(col0 + wid * 16 + l15) * lw + koff + sl * 8;
        GLOAD_LDS16(gw,      dst + 4096 + (wid * 2 + 0) * 512);
        GLOAD_LDS16(gw + 32, dst + 4096 + (wid * 2 + 1) * 512);
    };

    auto COMPUTE = [&](int t) {
        const ushort* base = &SB[t & 3][0];
        #pragma unroll
        for (int ks = 0; ks < 2; ++ks) {
            const bf16x8 a0 = *(const bf16x8*)&base[((wr*2 + 0)*2 + ks)*512 + lane*8];
            const bf16x8 a1 = *(const bf16x8*)&base[((wr*2 + 1)*2 + ks)*512 + lane*8];
            const bf16x8 b0 = *(const bf16x8*)&base[4096 + ((wc*2 + 0)*2 + ks)*512 + lane*8];
            const bf16x8 b1 = *(const bf16x8*)&base[4096 + ((wc*2 + 1)*2 + ks)*512 + lane*8];
            acc[0][0] = __builtin_amdgcn_mfma_f32_16x16x32_bf16(a0, b0, acc[0][0], 0, 0, 0);
            acc[0][1] = __builtin_amdgcn_mfma_f32_16x16x32_bf16(a0, b1, acc[0][1], 0, 0, 0);
            acc[1][0] = __builtin_amdgcn_mfma_f32_16x16x32_bf16(a1, b0, acc[1][0], 0, 0, 0);
            acc[1][1] = __builtin_amdgcn_mfma_f32_16x16x32_bf16(a1, b1, acc[1][1], 0, 0, 0);
        }
    };

    STAGE(0); STAGE(1); STAGE(2);
    int t = 0;
    for (; t < nt - 3; ++t) {
        STAGE(t + 3);
        VMW(12); RBAR();          // step t's loads complete
        COMPUTE(t);
        RBAR();                   // WAR: next STAGE reuses slot t%4
    }
    if (nt >= 3) { VMW(8); RBAR(); COMPUTE(nt - 3); }
    if (nt >= 2) { VMW(4); RBAR(); COMPUTE(nt - 2); }
    VMW(0); RBAR(); COMPUTE(nt - 1);

    #pragma unroll
    for (int fi = 0; fi < 2; ++fi)
        #pragma unroll
        for (int fj = 0; fj < 2; ++fj) {
            const int r0 = row0 + wr * 32 + fi * 16 + sl * 4;
            const int c  = col0 + wc * 32 + fj * 16 + l15;
            const float bb = bias ? bias[c] : 0.0f;
            #pragma unroll
            for (int r = 0; r < 4; ++r) {
                float v = acc[fi][fj][r] + bb;
                if (RELU) v = fmaxf(v, 0.0f);
                if (WF32) Cf[(size_t)(r0 + r) * ldc + c] = v;
                if (WBF)  Cb[(size_t)(r0 + r) * ldc + c] = f2bf(v);
            }
        }
}

extern "C" void kernel_launch(void* const* d_in, const int* in_sizes, int n_in,
                              void* d_out, int out_size, void* d_ws, size_t ws_size,
                              hipStream_t stream)
{
    (void)in_sizes; (void)n_in; (void)out_size;
    const int*   inputs = (const int*)  d_in[0];
    const float* masks  = (const float*)d_in[1];
    const float* embed  = (const float*)d_in[2];
    const float* w_ih0  = (const float*)d_in[3];
    const float* w_hh0  = (const float*)d_in[4];
    const float* b_ih0  = (const float*)d_in[5];
    const float* b_hh0  = (const float*)d_in[6];
    const float* w_ih1  = (const float*)d_in[7];
    const float* w_hh1  = (const float*)d_in[8];
    const float* b_ih1  = (const float*)d_in[9];
    const float* b_hh1  = (const float*)d_in[10];
    const float* w_d1   = (const float*)d_in[11];
    const float* b_d1   = (const float*)d_in[12];
    const float* w_d2   = (const float*)d_in[13];
    const float* b_d2   = (const float*)d_in[14];

    float* out    = (float*)d_out;
    float* xf_hat = out;                          // (B, D)
    float* xf     = out + (size_t)NB * ND;        // (B, D)
    float* lasth  = out + 2 * (size_t)NB * ND;    // (B, H)

    const size_t tbl_bytes  = TBL_ELEMS;                            // 25.6 MB
    const size_t part_bytes = (size_t)NB * NSEG * NSLICE * ND * 2;  // 32 MB
    const size_t cnt_bytes  = (size_t)NB * NSEG * NSLICE * 4;       // 128 KB
    const size_t rest_bytes = (size_t)1179648 * 2 + 4096
                            + (size_t)NB * NSEG * ND * 2
                            + 4 * (size_t)NB * NH * 2
                            + (size_t)NB * NDEC * 2;
    const bool bigws = ws_size >= tbl_bytes + part_bytes + cnt_bytes
                                + rest_bytes + 1024;

    char* ws = (char*)d_ws;
    unsigned* tb8 = nullptr; ushort* partial = nullptr; unsigned* cnts = nullptr;
    if (bigws) {
        tb8     = (unsigned*)ws; ws += tbl_bytes;
        partial = (ushort*)ws;   ws += part_bytes;
        cnts    = (unsigned*)ws; ws += cnt_bytes;
    }
    ushort* wbf   = (ushort*)ws;  ws += (size_t)1179648 * 2;
    float*  bsum0 = (float*)ws;   ws += 2048;
    float*  bsum1 = (float*)ws;   ws += 2048;
    ushort* xpool = (ushort*)ws;  ws += (size_t)NB * NSEG * ND * 2;
    ushort* h0a   = (ushort*)ws;  ws += (size_t)NB * NH * 2;
    ushort* h0b   = (ushort*)ws;  ws += (size_t)NB * NH * 2;
    ushort* h1a   = (ushort*)ws;  ws += (size_t)NB * NH * 2;
    ushort* h1b   = (ushort*)ws;  ws += (size_t)NB * NH * 2;
    ushort* dec1b = (ushort*)ws;  ws += (size_t)NB * NDEC * 2;

    const ushort* wih0 = wbf;
    const ushort* whh0 = wbf + 262144;
    const ushort* wih1 = wbf + 524288;
    const ushort* whh1 = wbf + 786432;
    const ushort* wd1  = wbf + 1048576;
    const ushort* wd2  = wbf + 1114112;

    convert_all<<<2048, 256, 0, stream>>>(embed, w_ih0, w_hh0, w_ih1, w_hh1,
                                          w_d1, w_d2, b_ih0, b_hh0, b_ih1, b_hh1,
                                          tb8, wbf, bsum0, bsum1, bigws ? 1 : 0);
    if (bigws) {
        poolA<<<(NB * NSEG / 4) * NSLICE, 256, 0, stream>>>(
            inputs, (const unsigned char*)tb8, masks, partial, cnts);
        poolB<<<NB * NSEG / 4, 256, 0, stream>>>(partial, cnts, masks, xpool, xf);
    } else {
        pool_fallback<<<NB * NSEG, 64, 0, stream>>>(inputs, embed, masks, xpool, xf);
    }

    const dim3 blk(256);
    const int nH  = (NH / 64)   * (NB / 64);   // 128 blocks, gx=8
    const int nD1 = (NDEC / 64) * (NB / 64);   // 32 blocks,  gx=2
    const int nD2 = (ND / 64)   * (NB / 64);   // 128 blocks, gx=8

    // RNN scan over past = [3, 2, 0]; h starts at zero (K1=0 on step 0).
    mfma_gemm<true,false,true><<<nH, blk, 0, stream>>>(
        xpool + 3 * ND, NSEG * ND, nullptr, 0, wih0, ND, nullptr, 0,
        bsum0, nullptr, h0a, NH, ND, 0, 8);
    mfma_gemm<true,false,true><<<nH, blk, 0, stream>>>(
        h0a, NH, nullptr, 0, wih1, NH, nullptr, 0,
        bsum1, nullptr, h1a, NH, NH, 0, 8);
    mfma_gemm<true,false,true><<<nH, blk, 0, stream>>>(
        xpool + 2 * ND, NSEG * ND, h0a, NH, wih0, ND, whh0, NH,
        bsum0, nullptr, h0b, NH, ND, NH, 8);
    mfma_gemm<true,false,true><<<nH, blk, 0, stream>>>(
        h0b, NH, h1a, NH, wih1, NH, whh1, NH,
        bsum1, nullptr, h1b, NH, NH, NH, 8);
    mfma_gemm<true,false,true><<<nH, blk, 0, stream>>>(
        xpool + 0 * ND, NSEG * ND, h0b, NH, wih0, ND, whh0, NH,
        bsum0, nullptr, h0a, NH, ND, NH, 8);
    mfma_gemm<true,true,true><<<nH, blk, 0, stream>>>(
        h0a, NH, h1b, NH, wih1, NH, whh1, NH,
        bsum1, lasth, h1a, NH, NH, NH, 8);        // fp32 last_h -> d_out, bf16 -> h1a

    // decoder
    mfma_gemm<true,false,true><<<nD1, blk, 0, stream>>>(
        h1a, NH, nullptr, 0, wd1, NH, nullptr, 0,
        b_d1, nullptr, dec1b, NDEC, NH, 0, 2);
    mfma_gemm<false,true,false><<<nD2, blk, 0, stream>>>(
        dec1b, NDEC, nullptr, 0, wd2, NDEC, nullptr, 0,
        b_d2, xf_hat, nullptr, ND, NDEC, 0, 8);
}

// Round 6
// 100.455 us; speedup vs baseline: 1.2144x; 1.2144x over previous
//
#include <hip/hip_runtime.h>
#include <hip/hip_bf16.h>

// B=1024, M=4 segments, L=100 tokens, D=512, V=50000, H=512, DEC_HID=128
constexpr int NB   = 1024;
constexpr int NSEG = 4;
constexpr int LSEQ = 100;
constexpr int ND   = 512;
constexpr int NH   = 512;
constexpr int NDEC = 128;
constexpr int NV   = 50000;
constexpr size_t TBL_ELEMS = (size_t)NV * ND;      // 25.6M elems

typedef __attribute__((ext_vector_type(8))) short bf16x8;
typedef __attribute__((ext_vector_type(4))) float f32x4;
typedef __attribute__((ext_vector_type(2))) float f32x2;
typedef __attribute__((ext_vector_type(8))) unsigned short u16x8;

__device__ __forceinline__ ushort f2bf(float f) {
    union { float f; unsigned u; } v; v.f = f;
    unsigned r = (v.u + 0x7fffu + ((v.u >> 16) & 1u)) >> 16;   // RNE
    return (ushort)r;
}
__device__ __forceinline__ float bf2f(ushort u) {
    return __uint_as_float((unsigned)u << 16);
}

// global -> LDS direct copy, 16 B per lane. LDS dest wave-uniform base;
// lane i lands at base + i*16. Global src is per-lane (fragment-ordered).
#define GLOAD_LDS16(gp, lp)                                                     \
    __builtin_amdgcn_global_load_lds(                                           \
        (const __attribute__((address_space(1))) unsigned int*)(gp),            \
        (__attribute__((address_space(3))) unsigned int*)(lp), 16, 0, 0)

#define VMW(N) asm volatile("s_waitcnt vmcnt(" #N ")" ::: "memory")
#define RBAR() do { __builtin_amdgcn_s_barrier();                               \
                    __builtin_amdgcn_sched_barrier(0); } while (0)

// ---------------------------------------------------------------------------
// One-shot conversion: embed table fp32->fp8 e4m3 (hardware cvt),
// 6 weight matrices fp32->bf16, RNN bias pairs pre-summed.
// ---------------------------------------------------------------------------
__global__ __launch_bounds__(256)
void convert_all(const float* __restrict__ table,
                 const float* __restrict__ w_ih0, const float* __restrict__ w_hh0,
                 const float* __restrict__ w_ih1, const float* __restrict__ w_hh1,
                 const float* __restrict__ w_d1,  const float* __restrict__ w_d2,
                 const float* __restrict__ b_ih0, const float* __restrict__ b_hh0,
                 const float* __restrict__ b_ih1, const float* __restrict__ b_hh1,
                 unsigned* __restrict__ tb8, ushort* __restrict__ wbf,
                 float* __restrict__ bsum0, float* __restrict__ bsum1,
                 int doTable)
{
    const size_t stride = (size_t)gridDim.x * blockDim.x;
    const size_t gid    = (size_t)blockIdx.x * blockDim.x + threadIdx.x;

    if (doTable) {
        const size_t nvec = TBL_ELEMS / 8;     // 8 floats -> 8 fp8 bytes
        for (size_t i = gid; i < nvec; i += stride) {
            const float4 a = ((const float4*)table)[2 * i];
            const float4 b = ((const float4*)table)[2 * i + 1];
            unsigned w0 = __builtin_amdgcn_cvt_pk_fp8_f32(a.x, a.y, 0, false);
            w0          = __builtin_amdgcn_cvt_pk_fp8_f32(a.z, a.w, w0, true);
            unsigned w1 = __builtin_amdgcn_cvt_pk_fp8_f32(b.x, b.y, 0, false);
            w1          = __builtin_amdgcn_cvt_pk_fp8_f32(b.z, b.w, w1, true);
            uint2 o; o.x = w0; o.y = w1;
            ((uint2*)tb8)[i] = o;
        }
    }
    constexpr int N0 = 512 * 512, ND2 = 128 * 512;
    constexpr int TOT = 4 * N0 + 2 * ND2 + 1024;
    for (size_t i = gid; i < TOT; i += stride) {
        if (i < 4 * (size_t)N0) {
            const float* src = (i < N0) ? w_ih0 : (i < 2*(size_t)N0) ? w_hh0
                             : (i < 3*(size_t)N0) ? w_ih1 : w_hh1;
            wbf[i] = f2bf(src[i & (N0 - 1)]);
        } else if (i < 4 * (size_t)N0 + ND2) {
            wbf[i] = f2bf(w_d1[i - 4 * (size_t)N0]);
        } else if (i < 4 * (size_t)N0 + 2 * ND2) {
            wbf[i] = f2bf(w_d2[i - 4 * (size_t)N0 - ND2]);
        } else {
            const int j = (int)(i - (4 * (size_t)N0 + 2 * ND2));
            if (j < 512) bsum0[j] = b_ih0[j] + b_hh0[j];
            else         bsum1[j - 512] = b_ih1[j - 512] + b_hh1[j - 512];
        }
    }
}

// ---------------------------------------------------------------------------
// Pooling: one wave per (b,m). Masked-out past segments (m!=1, mask==0)
// write a zero row and skip the gather entirely (reference multiplies x_t
// by 0). Otherwise: compact non-pad tokens via ballot, gather fp8 rows with
// 8 rows in flight per lane (8 B each), hardware cvt_pk_f32_fp8 unpack.
// m==1 -> fp32 x_future into d_out; else bf16 xpool.
// ---------------------------------------------------------------------------
__global__ __launch_bounds__(64)
void pool_fp8(const int* __restrict__ toks, const unsigned char* __restrict__ tb8,
              const float* __restrict__ masks,
              ushort* __restrict__ xpool, float* __restrict__ xfut)
{
    const int bm = blockIdx.x, m = bm & 3, lane = threadIdx.x;
    const int d  = lane * 8;

    if (m != 1 && masks[bm] == 0.0f) {         // x_t * 0 -> zero row
        u16x8 z = {};
        *(u16x8*)&xpool[(size_t)bm * ND + d] = z;
        return;
    }

    __shared__ int sidx[112];
    int cnt = 0;
    {
        const int t0 = __builtin_nontemporal_load(&toks[(size_t)bm * LSEQ + lane]);
        const unsigned long long m0 = __ballot(t0 != 0);
        const int p0 = __popcll(m0 & ((1ull << lane) - 1ull));
        if (t0 != 0) sidx[p0] = t0;
        cnt = __popcll(m0);
        int t1 = 0;
        if (lane < LSEQ - 64)
            t1 = __builtin_nontemporal_load(&toks[(size_t)bm * LSEQ + 64 + lane]);
        const unsigned long long m1 = __ballot(t1 != 0);
        const int p1 = __popcll(m1 & ((1ull << lane) - 1ull));
        if (t1 != 0) sidx[cnt + p1] = t1;
        cnt += __popcll(m1);
    }
    __syncthreads();

    float acc[8] = {};
    const size_t off = (size_t)lane * 8;
    int j = 0;
    for (; j + 8 <= cnt; j += 8) {
        uint2 v[8];
        #pragma unroll
        for (int u = 0; u < 8; ++u)
            v[u] = *(const uint2*)&tb8[(size_t)sidx[j + u] * ND + off];
        #pragma unroll
        for (int u = 0; u < 8; ++u) {
            const f32x2 p0 = __builtin_amdgcn_cvt_pk_f32_fp8(v[u].x, false);
            const f32x2 p1 = __builtin_amdgcn_cvt_pk_f32_fp8(v[u].x, true);
            const f32x2 p2 = __builtin_amdgcn_cvt_pk_f32_fp8(v[u].y, false);
            const f32x2 p3 = __builtin_amdgcn_cvt_pk_f32_fp8(v[u].y, true);
            acc[0] += p0[0]; acc[1] += p0[1]; acc[2] += p1[0]; acc[3] += p1[1];
            acc[4] += p2[0]; acc[5] += p2[1]; acc[6] += p3[0]; acc[7] += p3[1];
        }
    }
    for (; j < cnt; ++j) {
        const uint2 v = *(const uint2*)&tb8[(size_t)sidx[j] * ND + off];
        const f32x2 p0 = __builtin_amdgcn_cvt_pk_f32_fp8(v.x, false);
        const f32x2 p1 = __builtin_amdgcn_cvt_pk_f32_fp8(v.x, true);
        const f32x2 p2 = __builtin_amdgcn_cvt_pk_f32_fp8(v.y, false);
        const f32x2 p3 = __builtin_amdgcn_cvt_pk_f32_fp8(v.y, true);
        acc[0] += p0[0]; acc[1] += p0[1]; acc[2] += p1[0]; acc[3] += p1[1];
        acc[4] += p2[0]; acc[5] += p2[1]; acc[6] += p3[0]; acc[7] += p3[1];
    }

    const float inv = 1.0f / (float)(cnt > 0 ? cnt : 1);
    if (m == 1) {
        float* dst = &xfut[(size_t)(bm >> 2) * ND + d];
        float4 o0 = {acc[0]*inv, acc[1]*inv, acc[2]*inv, acc[3]*inv};
        float4 o1 = {acc[4]*inv, acc[5]*inv, acc[6]*inv, acc[7]*inv};
        *(float4*)dst = o0; *(float4*)(dst + 4) = o1;
    } else {
        u16x8 o;
        #pragma unroll
        for (int e = 0; e < 8; ++e) o[e] = f2bf(acc[e] * inv);
        *(u16x8*)&xpool[(size_t)bm * ND + d] = o;
    }
}

// ---------------------------------------------------------------------------
// Fallback single-phase pool (fp32 table) if workspace is too small.
// ---------------------------------------------------------------------------
__global__ __launch_bounds__(64)
void pool_fallback(const int* __restrict__ toks, const float* __restrict__ tb,
                   const float* __restrict__ masks,
                   ushort* __restrict__ xpool, float* __restrict__ xfut)
{
    const int bm = blockIdx.x, m = bm & 3, lane = threadIdx.x;
    const int d  = lane * 8;
    if (m != 1 && masks[bm] == 0.0f) {
        u16x8 z = {};
        *(u16x8*)&xpool[(size_t)bm * ND + d] = z;
        return;
    }
    __shared__ int sidx[112];
    int cnt = 0;
    {
        const int t0 = toks[(size_t)bm * LSEQ + lane];
        const unsigned long long m0 = __ballot(t0 != 0);
        const int p0 = __popcll(m0 & ((1ull << lane) - 1ull));
        if (t0 != 0) sidx[p0] = t0;
        cnt = __popcll(m0);
        const int t1 = (lane < LSEQ - 64) ? toks[(size_t)bm * LSEQ + 64 + lane] : 0;
        const unsigned long long m1 = __ballot(t1 != 0);
        const int p1 = __popcll(m1 & ((1ull << lane) - 1ull));
        if (t1 != 0) sidx[cnt + p1] = t1;
        cnt += __popcll(m1);
    }
    __syncthreads();
    float acc[8] = {};
    for (int j = 0; j < cnt; ++j) {
        const float4 a = *(const float4*)&tb[(size_t)sidx[j] * ND + d];
        const float4 b = *(const float4*)&tb[(size_t)sidx[j] * ND + d + 4];
        acc[0] += a.x; acc[1] += a.y; acc[2] += a.z; acc[3] += a.w;
        acc[4] += b.x; acc[5] += b.y; acc[6] += b.z; acc[7] += b.w;
    }
    const float inv = 1.0f / (float)(cnt > 0 ? cnt : 1);
    if (m == 1) {
        float* dst = &xfut[(size_t)(bm >> 2) * ND + d];
        float4 o0 = {acc[0]*inv, acc[1]*inv, acc[2]*inv, acc[3]*inv};
        float4 o1 = {acc[4]*inv, acc[5]*inv, acc[6]*inv, acc[7]*inv};
        *(float4*)dst = o0; *(float4*)(dst + 4) = o1;
    } else {
        u16x8 o;
        #pragma unroll
        for (int e = 0; e < 8; ++e) o[e] = f2bf(acc[e] * inv);
        *(u16x8*)&xpool[(size_t)bm * ND + d] = o;
    }
}

// ---------------------------------------------------------------------------
// bf16 MFMA GEMM, pipelined, DUAL-descriptor: one dispatch runs up to two
// independent GEMMs (blocks [0,n0) -> da, [n0,grid) -> db). Each half keeps
// its own chunked XCD swizzle (valid because n0 % 8 == 0).
// C = act( [A0, A1] @ [W0, W1]^T + bias ), 64x64 tile, BK=64, 4 waves,
// 4-slot LDS pipeline, counted vmcnt(12) + raw s_barrier, peeled tail.
// ---------------------------------------------------------------------------
struct GDesc {
    const ushort *A0, *A1, *W0, *W1;
    const float  *bias;
    float        *Cf;
    ushort       *Cb;
    int lda0, lda1, ldw0, ldw1, ldc, K0, K1, gx;
};

template<bool RELU, bool WF32, bool WBF>
__global__ __launch_bounds__(256)
void mfma_gemm2(GDesc da, GDesc db, int n0)
{
    __shared__ ushort SB[4][8192];    // 4 slots x (A 8KB | W 8KB)
    const bool second = ((int)blockIdx.x >= n0);
    const GDesc d   = second ? db : da;
    const int   lb  = second ? (int)blockIdx.x - n0 : (int)blockIdx.x;
    const int  nloc = second ? (int)gridDim.x - n0 : n0;

    const int tid  = threadIdx.x;
    const int lane = tid & 63;
    const int wid  = tid >> 6;        // 0..3
    const int l15  = lane & 15;
    const int sl   = lane >> 4;       // k-chunk slot within 32-k group
    const int wr   = wid >> 1;        // quadrant row (0/1)
    const int wc   = wid & 1;         // quadrant col (0/1)

    const int per  = nloc >> 3;
    const int tile = (lb & 7) * per + (lb >> 3);  // chunked XCD swizzle
    const int row0 = (tile / d.gx) * 64;
    const int col0 = (tile % d.gx) * 64;
    const int nt   = (d.K0 + d.K1) >> 6;  // K-steps of 64

    f32x4 acc[2][2] = {};

    auto STAGE = [&](int t) {
        if (t >= nt) return;
        const int kg   = t * 64;
        const int ph   = (kg >= d.K0);
        const int koff = ph ? kg - d.K0 : kg;
        const ushort* Ap = ph ? d.A1 : d.A0;
        const int     la = ph ? d.lda1 : d.lda0;
        const ushort* Wp = ph ? d.W1 : d.W0;
        const int     lw = ph ? d.ldw1 : d.ldw0;
        ushort* dst = &SB[t & 3][0];
        const ushort* ga = Ap + (size_t)(row0 + wid * 16 + l15) * la + koff + sl * 8;
        GLOAD_LDS16(ga,      dst + (wid * 2 + 0) * 512);
        GLOAD_LDS16(ga + 32, dst + (wid * 2 + 1) * 512);
        const ushort* gw = Wp + (size_t)(col0 + wid * 16 + l15) * lw + koff + sl * 8;
        GLOAD_LDS16(gw,      dst + 4096 + (wid * 2 + 0) * 512);
        GLOAD_LDS16(gw + 32, dst + 4096 + (wid * 2 + 1) * 512);
    };

    auto COMPUTE = [&](int t) {
        const ushort* base = &SB[t & 3][0];
        #pragma unroll
        for (int ks = 0; ks < 2; ++ks) {
            const bf16x8 a0 = *(const bf16x8*)&base[((wr*2 + 0)*2 + ks)*512 + lane*8];
            const bf16x8 a1 = *(const bf16x8*)&base[((wr*2 + 1)*2 + ks)*512 + lane*8];
            const bf16x8 b0 = *(const bf16x8*)&base[4096 + ((wc*2 + 0)*2 + ks)*512 + lane*8];
            const bf16x8 b1 = *(const bf16x8*)&base[4096 + ((wc*2 + 1)*2 + ks)*512 + lane*8];
            acc[0][0] = __builtin_amdgcn_mfma_f32_16x16x32_bf16(a0, b0, acc[0][0], 0, 0, 0);
            acc[0][1] = __builtin_amdgcn_mfma_f32_16x16x32_bf16(a0, b1, acc[0][1], 0, 0, 0);
            acc[1][0] = __builtin_amdgcn_mfma_f32_16x16x32_bf16(a1, b0, acc[1][0], 0, 0, 0);
            acc[1][1] = __builtin_amdgcn_mfma_f32_16x16x32_bf16(a1, b1, acc[1][1], 0, 0, 0);
        }
    };

    STAGE(0); STAGE(1); STAGE(2);
    int t = 0;
    for (; t < nt - 3; ++t) {
        STAGE(t + 3);
        VMW(12); RBAR();          // step t's loads complete
        COMPUTE(t);
        RBAR();                   // WAR: next STAGE reuses slot t%4
    }
    if (nt >= 3) { VMW(8); RBAR(); COMPUTE(nt - 3); }
    if (nt >= 2) { VMW(4); RBAR(); COMPUTE(nt - 2); }
    VMW(0); RBAR(); COMPUTE(nt - 1);

    #pragma unroll
    for (int fi = 0; fi < 2; ++fi)
        #pragma unroll
        for (int fj = 0; fj < 2; ++fj) {
            const int r0 = row0 + wr * 32 + fi * 16 + sl * 4;
            const int c  = col0 + wc * 32 + fj * 16 + l15;
            const float bb = d.bias ? d.bias[c] : 0.0f;
            #pragma unroll
            for (int r = 0; r < 4; ++r) {
                float v = acc[fi][fj][r] + bb;
                if (RELU) v = fmaxf(v, 0.0f);
                if (WF32) d.Cf[(size_t)(r0 + r) * d.ldc + c] = v;
                if (WBF)  d.Cb[(size_t)(r0 + r) * d.ldc + c] = f2bf(v);
            }
        }
}

extern "C" void kernel_launch(void* const* d_in, const int* in_sizes, int n_in,
                              void* d_out, int out_size, void* d_ws, size_t ws_size,
                              hipStream_t stream)
{
    (void)in_sizes; (void)n_in; (void)out_size;
    const int*   inputs = (const int*)  d_in[0];
    const float* masks  = (const float*)d_in[1];
    const float* embed  = (const float*)d_in[2];
    const float* w_ih0  = (const float*)d_in[3];
    const float* w_hh0  = (const float*)d_in[4];
    const float* b_ih0  = (const float*)d_in[5];
    const float* b_hh0  = (const float*)d_in[6];
    const float* w_ih1  = (const float*)d_in[7];
    const float* w_hh1  = (const float*)d_in[8];
    const float* b_ih1  = (const float*)d_in[9];
    const float* b_hh1  = (const float*)d_in[10];
    const float* w_d1   = (const float*)d_in[11];
    const float* b_d1   = (const float*)d_in[12];
    const float* w_d2   = (const float*)d_in[13];
    const float* b_d2   = (const float*)d_in[14];

    float* out    = (float*)d_out;
    float* xf_hat = out;                          // (B, D)
    float* xf     = out + (size_t)NB * ND;        // (B, D)
    float* lasth  = out + 2 * (size_t)NB * ND;    // (B, H)

    const size_t tbl_bytes  = TBL_ELEMS;                            // 25.6 MB
    const size_t rest_bytes = (size_t)1179648 * 2 + 4096
                            + (size_t)NB * NSEG * ND * 2
                            + 4 * (size_t)NB * NH * 2
                            + (size_t)NB * NDEC * 2;
    const bool bigws = ws_size >= tbl_bytes + rest_bytes + 1024;

    char* ws = (char*)d_ws;
    unsigned* tb8 = nullptr;
    if (bigws) { tb8 = (unsigned*)ws; ws += tbl_bytes; }
    ushort* wbf   = (ushort*)ws;  ws += (size_t)1179648 * 2;
    float*  bsum0 = (float*)ws;   ws += 2048;
    float*  bsum1 = (float*)ws;   ws += 2048;
    ushort* xpool = (ushort*)ws;  ws += (size_t)NB * NSEG * ND * 2;
    ushort* h0a   = (ushort*)ws;  ws += (size_t)NB * NH * 2;
    ushort* h0b   = (ushort*)ws;  ws += (size_t)NB * NH * 2;
    ushort* h1a   = (ushort*)ws;  ws += (size_t)NB * NH * 2;
    ushort* h1b   = (ushort*)ws;  ws += (size_t)NB * NH * 2;
    ushort* dec1b = (ushort*)ws;  ws += (size_t)NB * NDEC * 2;

    const ushort* wih0 = wbf;
    const ushort* whh0 = wbf + 262144;
    const ushort* wih1 = wbf + 524288;
    const ushort* whh1 = wbf + 786432;
    const ushort* wd1  = wbf + 1048576;
    const ushort* wd2  = wbf + 1114112;

    convert_all<<<2048, 256, 0, stream>>>(embed, w_ih0, w_hh0, w_ih1, w_hh1,
                                          w_d1, w_d2, b_ih0, b_hh0, b_ih1, b_hh1,
                                          tb8, wbf, bsum0, bsum1, bigws ? 1 : 0);
    if (bigws)
        pool_fp8<<<NB * NSEG, 64, 0, stream>>>(inputs, (const unsigned char*)tb8,
                                               masks, xpool, xf);
    else
        pool_fallback<<<NB * NSEG, 64, 0, stream>>>(inputs, embed, masks, xpool, xf);

    const dim3 blk(256);
    const int nH  = (NH / 64)   * (NB / 64);   // 128 blocks per GEMM, gx=8
    const int nD1 = (NDEC / 64) * (NB / 64);   // 32 blocks,  gx=2
    const int nD2 = (ND / 64)   * (NB / 64);   // 128 blocks, gx=8

    auto mk = [](const ushort* A0, int lda0, const ushort* A1, int lda1,
                 const ushort* W0, int ldw0, const ushort* W1, int ldw1,
                 const float* bias, float* Cf, ushort* Cb, int ldc,
                 int K0, int K1, int gx) {
        GDesc g; g.A0 = A0; g.A1 = A1; g.W0 = W0; g.W1 = W1; g.bias = bias;
        g.Cf = Cf; g.Cb = Cb; g.lda0 = lda0; g.lda1 = lda1; g.ldw0 = ldw0;
        g.ldw1 = ldw1; g.ldc = ldc; g.K0 = K0; g.K1 = K1; g.gx = gx;
        return g;
    };

    // RNN scan over past = [3, 2, 0]; h starts at zero (K1=0 on step 0).
    // DAG: G1 -> {G2, G3} -> {G4, G5} -> G6 -> D1 -> D2.
    const GDesc G1 = mk(xpool + 3 * ND, NSEG * ND, nullptr, 0,
                        wih0, ND, nullptr, 0, bsum0, nullptr, h0a, NH, ND, 0, 8);
    const GDesc G2 = mk(h0a, NH, nullptr, 0,
                        wih1, NH, nullptr, 0, bsum1, nullptr, h1a, NH, NH, 0, 8);
    const GDesc G3 = mk(xpool + 2 * ND, NSEG * ND, h0a, NH,
                        wih0, ND, whh0, NH, bsum0, nullptr, h0b, NH, ND, NH, 8);
    const GDesc G4 = mk(h0b, NH, h1a, NH,
                        wih1, NH, whh1, NH, bsum1, nullptr, h1b, NH, NH, NH, 8);
    const GDesc G5 = mk(xpool + 0 * ND, NSEG * ND, h0b, NH,
                        wih0, ND, whh0, NH, bsum0, nullptr, h0a, NH, ND, NH, 8);
    const GDesc G6 = mk(h0a, NH, h1b, NH,
                        wih1, NH, whh1, NH, bsum1, lasth, h1a, NH, NH, NH, 8);
    const GDesc D1 = mk(h1a, NH, nullptr, 0,
                        wd1, NH, nullptr, 0, b_d1, nullptr, dec1b, NDEC, NH, 0, 2);
    const GDesc D2 = mk(dec1b, NDEC, nullptr, 0,
                        wd2, NDEC, nullptr, 0, b_d2, xf_hat, nullptr, ND, NDEC, 0, 8);

    mfma_gemm2<true,false,true><<<nH,      blk, 0, stream>>>(G1, G1, nH);
    mfma_gemm2<true,false,true><<<2 * nH,  blk, 0, stream>>>(G2, G3, nH);
    mfma_gemm2<true,false,true><<<2 * nH,  blk, 0, stream>>>(G4, G5, nH);
    mfma_gemm2<true,true, true><<<nH,      blk, 0, stream>>>(G6, G6, nH);
    mfma_gemm2<true,false,true><<<nD1,     blk, 0, stream>>>(D1, D1, nD1);
    mfma_gemm2<false,true,false><<<nD2,    blk, 0, stream>>>(D2, D2, nD2);
}